// Round 13
// baseline (145.577 us; speedup 1.0000x reference)
//
#include <hip/hip_runtime.h>

typedef _Float16 h2 __attribute__((ext_vector_type(2)));
typedef _Float16 h8 __attribute__((ext_vector_type(8)));

#define WSTRIDE 108   // dwords per position in weight LDS (27 taps x 4 dwords)

// ---- DPP wave-64 sum (VALU pipe): full sum lands in lane 63 ----
template <int CTRL>
__device__ __forceinline__ float dpp_stage(float v) {
    int x = __builtin_amdgcn_update_dpp(0, __float_as_int(v), CTRL, 0xf, 0xf, true);
    return v + __int_as_float(x);
}
__device__ __forceinline__ float wave_sum(float v) {
    v = dpp_stage<0x111>(v);  // row_shr:1
    v = dpp_stage<0x112>(v);  // row_shr:2
    v = dpp_stage<0x114>(v);  // row_shr:4
    v = dpp_stage<0x118>(v);  // row_shr:8
    v = dpp_stage<0x142>(v);  // row_bcast:15
    v = dpp_stage<0x143>(v);  // row_bcast:31
    return v;
}
__device__ __forceinline__ float bcast63(float v) {
    return __int_as_float(__builtin_amdgcn_readlane(__float_as_int(v), 63));
}
__device__ __forceinline__ h2 mid2(h2 lo, h2 hi) {
    int r = __builtin_amdgcn_alignbit(__builtin_bit_cast(int, hi),
                                      __builtin_bit_cast(int, lo), 16);
    return __builtin_bit_cast(h2, r);
}
__device__ __forceinline__ h2 pkrtz(float a, float b) {
    return __builtin_bit_cast(h2, __builtin_amdgcn_cvt_pkrtz(a, b));
}

// Compiler-level memory fence (emits nothing): pins LDS op program order for
// the single-wave read/write discipline on the private data buffer (round-1
// stale-neighbor bug; validated PASS r2/r3/r10/r12).
#define MEMFENCE() asm volatile("" ::: "memory")

// Zero-instruction register pin: forces W into VGPRs as an asm RESULT, which
// LLVM can never rematerialize (the r9/r10 failure) and never turn back into
// per-iteration LDS reads (the r12 cost). Non-volatile -> fully schedulable
// (unlike r11's accvgpr serialization).
#define PIN(W) asm("" : "+v"(W))

// h2 slice k (elements 2k,2k+1) of an h8 — register-select, no instructions
#define SL(W, K) __builtin_shufflevector(W, W, 2*(K), 2*(K)+1)

#define R27(M) M(0) M(1) M(2) M(3) M(4) M(5) M(6) M(7) M(8) M(9) M(10) M(11) \
    M(12) M(13) M(14) M(15) M(16) M(17) M(18) M(19) M(20) M(21) M(22) M(23)  \
    M(24) M(25) M(26)

// one-time: LDS -> register + pin + rounded-weight sums
#define LW(T)                                                                  \
    h8 w##T = wp8[(T)];                                                        \
    PIN(w##T);                                                                 \
    sw0 += (float)w##T[0]; sw1 += (float)w##T[1];                              \
    sw2 += (float)w##T[2]; sw3 += (float)w##T[3];                              \
    sw4 += (float)w##T[4]; sw5 += (float)w##T[5];                              \
    sw6 += (float)w##T[6]; sw7 += (float)w##T[7];

// one window column at data-dword offset O, weight registers WA,WB,WC:
// 5 LDS dword data reads + 4 alignbit + 36 v_pk_fma_f16 -> all 8 z outputs.
// ZERO weight-LDS traffic in the loop (r12 paid 27 ds_read_b128 per iter).
#define COLT(O, WA, WB, WC) {                                                  \
    h2 D0 = bp[(O) + 0], D1 = bp[(O) + 1], D2 = bp[(O) + 2],                   \
       D3 = bp[(O) + 3], D4 = bp[(O) + 4];                                     \
    h2 M0 = mid2(D0, D1), M1 = mid2(D1, D2), M2 = mid2(D2, D3),                \
       M3 = mid2(D3, D4);                                                      \
    dd0 = __builtin_elementwise_fma(D0, SL(WA, 0), dd0);                       \
    dd1 = __builtin_elementwise_fma(D1, SL(WA, 1), dd1);                       \
    dd2 = __builtin_elementwise_fma(D2, SL(WA, 2), dd2);                       \
    dd3 = __builtin_elementwise_fma(D3, SL(WA, 3), dd3);                       \
    dd0 = __builtin_elementwise_fma(M0, SL(WB, 0), dd0);                       \
    dd1 = __builtin_elementwise_fma(M1, SL(WB, 1), dd1);                       \
    dd2 = __builtin_elementwise_fma(M2, SL(WB, 2), dd2);                       \
    dd3 = __builtin_elementwise_fma(M3, SL(WB, 3), dd3);                       \
    dd0 = __builtin_elementwise_fma(D1, SL(WC, 0), dd0);                       \
    dd1 = __builtin_elementwise_fma(D2, SL(WC, 1), dd1);                       \
    dd2 = __builtin_elementwise_fma(D3, SL(WC, 2), dd2);                       \
    dd3 = __builtin_elementwise_fma(D4, SL(WC, 3), dd3); }

// normalized-dot correction + bias + silu + residual for one output
#define OUTK(CK, DDF, SWK, BK, RK) {                                           \
    float u = fmaf(fmaf(SWK, nmean, DDF), istd, BK);                           \
    CK += RK * (u * __builtin_amdgcn_rcpf(1.f + __expf(-u))); }

__global__ __launch_bounds__(256, 1)
void gridnet_kernel(const float* __restrict__ W,
                    const float* __restrict__ Bias,
                    const float* __restrict__ Rs,
                    const float* __restrict__ X,
                    float* __restrict__ Y,
                    int n_batch)
{
    // weights: 64 positions x 27 taps x 8 f16, staged once, SHARED by 4 waves
    __shared__ __align__(16) int wlds[64 * WSTRIDE];    // 27.6 KB
    // data: one private 10x10x10 f16 block per wave (batch)
    __shared__ __align__(16) h2 dbuf[4][500];           // 4 x 2 KB

    const int tid  = threadIdx.x;      // 256 threads = 4 independent waves
    const int wave = tid >> 6;
    const int lane = tid & 63;
    const int lx   = lane >> 3;        // 0..7
    const int ly   = lane & 7;

    // wave = one batch of the tile; 4 batches/wg share the weight staging.
    const int nq    = n_batch >> 2;
    const int bid   = (int)blockIdx.x;
    const int r     = bid / nq;                 // spatial block 0..511
    const int qb    = bid - r * nq;
    const int batch = 4 * qb + wave;
    const int gm0 = (r >> 6) << 3;
    const int gn0 = ((r >> 3) & 7) << 3;
    const int gk0 = (r & 7) << 3;

    const float* xb = X + ((size_t)batch << 18);
    h2* const my = dbuf[wave];

    // -------- data staging (per wave, own batch); stats on rounded ----------
    float s_all = 0.f, q_all = 0.f, s_int = 0.f, q_int = 0.f;
    #pragma unroll 1
    for (int c = lane; c < 100; c += 64) {
        int x = c / 10, y = c - (c / 10) * 10;   // padded coords 0..9
        int m = gm0 + x - 1, n = gn0 + y - 1;
        bool row_ok = ((unsigned)m < 64u) & ((unsigned)n < 64u);
        float4 fa = {0.f, 0.f, 0.f, 0.f}, fb = {0.f, 0.f, 0.f, 0.f};
        float vz0 = 0.f, vz9 = 0.f;
        if (row_ok) {
            const float* rp = xb + (m * 4096 + n * 64);
            fa = *(const float4*)(rp + gk0);          // z = 1..4
            fb = *(const float4*)(rp + gk0 + 4);      // z = 5..8
            if (gk0 > 0)  vz0 = rp[gk0 - 1];          // uniform branches
            if (gk0 < 56) vz9 = rp[gk0 + 8];
        }
        h2 d0 = pkrtz(vz0, fa.x), d1 = pkrtz(fa.y, fa.z), d2 = pkrtz(fa.w, fb.x),
           d3 = pkrtz(fb.y, fb.z), d4 = pkrtz(fb.w, vz9);
        my[c * 5 + 0] = d0; my[c * 5 + 1] = d1; my[c * 5 + 2] = d2;
        my[c * 5 + 3] = d3; my[c * 5 + 4] = d4;
        float t0 = (float)d0.x, t1 = (float)d0.y, t2 = (float)d1.x,
              t3 = (float)d1.y, t4 = (float)d2.x, t5 = (float)d2.y,
              t6 = (float)d3.x, t7 = (float)d3.y, t8 = (float)d4.x,
              t9 = (float)d4.y;
        float s8 = t1 + t2 + t3 + t4 + t5 + t6 + t7 + t8;
        float q8 = t1*t1 + t2*t2 + t3*t3 + t4*t4 + t5*t5 + t6*t6 + t7*t7 + t8*t8;
        s_all += s8 + t0 + t9;
        q_all += q8 + t0*t0 + t9*t9;
        bool inter = ((unsigned)(x - 1) < 8u) & ((unsigned)(y - 1) < 8u);
        if (inter) { s_int += s8; q_int += q8; }
    }

    // -------- cooperative weight staging: 27 taps x 64 positions ------------
    #pragma unroll 1
    for (int j = tid; j < 1728; j += 256) {
        int tap = j >> 6;                   // 0..26
        int pos = j & 63;
        int plx = pos >> 3, ply = pos & 7;
        const float* wp = W + ((size_t)tap << 18)
                        + (((size_t)(gm0 + plx)) << 12) + ((gn0 + ply) << 6) + gk0;
        float4 fa = *(const float4*)(wp);
        float4 fb = *(const float4*)(wp + 4);
        int4 v = { __builtin_bit_cast(int, pkrtz(fa.x, fa.y)),
                   __builtin_bit_cast(int, pkrtz(fa.z, fa.w)),
                   __builtin_bit_cast(int, pkrtz(fb.x, fb.y)),
                   __builtin_bit_cast(int, pkrtz(fb.z, fb.w)) };
        *(int4*)&wlds[pos * WSTRIDE + tap * 4] = v;     // aligned ds_write_b128
    }

    // -------- per-wave block stats: DPP + readlane only ---------------------
    float S_all = bcast63(wave_sum(s_all));
    float Q_all = bcast63(wave_sum(q_all));
    float Si    = bcast63(wave_sum(s_int));
    float Qi    = bcast63(wave_sum(q_int));
    const float halo_s = S_all - Si;
    const float halo_q = Q_all - Qi;

    __syncthreads();   // the ONLY barrier: weights visible to all 4 waves

    // -------- weights: LDS -> 108 pinned VGPRs (once), rounded sw sums ------
    const h8* const wp8 = (const h8*)&wlds[lane * WSTRIDE];
    float sw0=0.f, sw1=0.f, sw2=0.f, sw3=0.f, sw4=0.f, sw5=0.f, sw6=0.f, sw7=0.f;
    R27(LW)

    h2* const bp = &my[5 * (lx * 10 + ly)];   // window corner; own col = +55

    const size_t ofs = (((size_t)(gm0 + lx)) << 12) + ((gn0 + ly) << 6) + gk0;
    float4 ba = *(const float4*)(Bias + ofs), bb = *(const float4*)(Bias + ofs + 4);
    float4 ra = *(const float4*)(Rs + ofs),   rb = *(const float4*)(Rs + ofs + 4);

    // own column initial state (rounded values from LDS)
    h2 e0 = bp[55], e1 = bp[56], e2 = bp[57], e3 = bp[58], e4 = bp[59];
    float z0f = (float)e0.x, z9f = (float)e4.y;       // frozen z-halo halves
    float c1 = (float)e0.y, c2 = (float)e1.x, c3 = (float)e1.y, c4 = (float)e2.x,
          c5 = (float)e2.y, c6 = (float)e3.x, c7 = (float)e3.y, c8 = (float)e4.x;

    const float inv_n = 1.0f / 1000.0f;

    // 8 iterations, ZERO barriers (single-wave discipline + fences)
    #pragma unroll 1
    for (int it = 0; it < 8; ++it) {
        float mean  = (halo_s + Si) * inv_n;
        float qmean = (halo_q + Qi) * inv_n;
        float istd  = rsqrtf(qmean - mean * mean + 1e-5f);
        float nmean = -mean;

        h2 dd0 = { (_Float16)0.f, (_Float16)0.f };
        h2 dd1 = dd0, dd2 = dd0, dd3 = dd0;
        COLT(0,   w0,  w1,  w2)
        COLT(5,   w3,  w4,  w5)
        COLT(10,  w6,  w7,  w8)
        COLT(50,  w9,  w10, w11)
        COLT(55,  w12, w13, w14)
        COLT(60,  w15, w16, w17)
        COLT(100, w18, w19, w20)
        COLT(105, w21, w22, w23)
        COLT(110, w24, w25, w26)

        MEMFENCE();  // all column reads issue before the stores below

        OUTK(c1, (float)dd0.x, sw0, ba.x, ra.x)
        OUTK(c2, (float)dd0.y, sw1, ba.y, ra.y)
        OUTK(c3, (float)dd1.x, sw2, ba.z, ra.z)
        OUTK(c4, (float)dd1.y, sw3, ba.w, ra.w)
        OUTK(c5, (float)dd2.x, sw4, bb.x, rb.x)
        OUTK(c6, (float)dd2.y, sw5, bb.y, rb.y)
        OUTK(c7, (float)dd3.x, sw6, bb.z, rb.z)
        OUTK(c8, (float)dd3.y, sw7, bb.w, rb.w)

        if (it != 7) {   // last iteration: no writeback, no stats
            e0 = pkrtz(z0f, c1); e1 = pkrtz(c2, c3); e2 = pkrtz(c4, c5);
            e3 = pkrtz(c6, c7); e4 = pkrtz(c8, z9f);
            bp[55] = e0; bp[56] = e1; bp[57] = e2; bp[58] = e3; bp[59] = e4;

            MEMFENCE();  // stores stay above next iteration's reads

            float sp = ((c1 + c2) + (c3 + c4)) + ((c5 + c6) + (c7 + c8));
            float qp = ((c1*c1 + c2*c2) + (c3*c3 + c4*c4)) +
                       ((c5*c5 + c6*c6) + (c7*c7 + c8*c8));
            Si = bcast63(wave_sum(sp));
            Qi = bcast63(wave_sum(qp));
        }
    }

    float* yp = Y + ((size_t)batch << 18) + ofs;
    *(float4*)(yp)     = make_float4(c1, c2, c3, c4);
    *(float4*)(yp + 4) = make_float4(c5, c6, c7, c8);
}

extern "C" void kernel_launch(void* const* d_in, const int* in_sizes, int n_in,
                              void* d_out, int out_size, void* d_ws, size_t ws_size,
                              hipStream_t stream) {
    const float* W = (const float*)d_in[0];   // (27,64,64,64)
    const float* B = (const float*)d_in[1];   // (64,64,64)
    const float* R = (const float*)d_in[2];   // (64,64,64)
    const float* X = (const float*)d_in[3];   // (16,64,64,64)
    float* Y = (float*)d_out;

    int n_batch = in_sizes[3] >> 18;          // 64^3 per sample (16, div by 4)
    dim3 grid(512 * (n_batch >> 2)), block(256);
    hipLaunchKernelGGL(gridnet_kernel, grid, block, 0, stream, W, B, R, X, Y, n_batch);
}